// Round 1
// baseline (361.174 us; speedup 1.0000x reference)
//
#include <hip/hip_runtime.h>
#include <hip/hip_bf16.h>

#define DEV static __device__ __forceinline__

typedef __attribute__((ext_vector_type(4))) float f32x4;
typedef __attribute__((ext_vector_type(8))) short bf16x8;

constexpr int Bb = 4, Ts = 2048, Cc = 1024, Hh = 16, Dd = 64;
constexpr int Mm = Bb * Ts;   // 8192

union frag_u {
  bf16x8 f;
  uint2  u2[2];
  ushort us[8];
  uint4  u4;
};

union u4us {
  uint4 v;
  ushort us[8];
};

DEV ushort f2bf(float x) {
  union { float f; unsigned u; } v; v.f = x;
  unsigned r = v.u + 0x7FFFu + ((v.u >> 16) & 1u);
  return (ushort)(r >> 16);
}

// ---- swizzled LDS helpers: tile rows are 64 bf16 = 128 bytes; XOR 16B-chunk
// index with (row&7) to kill the row-major same-bank conflict (G4).
DEV int swz_off(int row, int bytecol) {
  return row * 128 + ((((bytecol >> 4) ^ (row & 7)) << 4) | (bytecol & 15));
}
DEV uint2 lds_ld64(const ushort* lds, int row, int colbf) {
  int off = swz_off(row, colbf << 1);
  return *reinterpret_cast<const uint2*>(reinterpret_cast<const char*>(lds) + off);
}
DEV void lds_st128(ushort* lds, int row, int c16, uint4 v) {
  int off = row * 128 + ((c16 ^ (row & 7)) << 4);
  *reinterpret_cast<uint4*>(reinterpret_cast<char*>(lds) + off) = v;
}
DEV void lds_st16(ushort* lds, int row, int colbf, ushort v) {
  int off = swz_off(row, colbf << 1);
  *reinterpret_cast<ushort*>(reinterpret_cast<char*>(lds) + off) = v;
}

// load one A/B fragment (two K=16 halves) from a swizzled [rows][64] tile
DEV void ld_frag(frag_u& fr, const ushort* lds, int row, int ks, int g) {
  fr.u2[0] = lds_ld64(lds, row, ks * 32 + 4 * g);
  fr.u2[1] = lds_ld64(lds, row, ks * 32 + 16 + 4 * g);
}

// ---------------------------------------------------------------- convert h
__global__ __launch_bounds__(256) void cvt_kernel(const float* __restrict__ in,
                                                  ushort* __restrict__ out, int n4) {
  for (int i = blockIdx.x * blockDim.x + threadIdx.x; i < n4;
       i += gridDim.x * blockDim.x) {
    float4 v = reinterpret_cast<const float4*>(in)[i];
    ushort4 o;
    o.x = f2bf(v.x); o.y = f2bf(v.y); o.z = f2bf(v.z); o.w = f2bf(v.w);
    reinterpret_cast<ushort4*>(out)[i] = o;
  }
}

// ------------------------------------------- transpose+convert weight to bf16
// in[R][Ccols] fp32 -> out[Ccols][R] bf16
__global__ __launch_bounds__(256) void transpose_cvt(const float* __restrict__ in,
                                                     ushort* __restrict__ out,
                                                     int R, int Ccols) {
  __shared__ float tile[32][33];
  int c0 = blockIdx.x * 32, r0 = blockIdx.y * 32;
  int tx = threadIdx.x & 31, ty = threadIdx.x >> 5;
#pragma unroll
  for (int i = 0; i < 4; ++i) {
    int r = ty + i * 8;
    tile[r][tx] = in[(size_t)(r0 + r) * Ccols + c0 + tx];
  }
  __syncthreads();
#pragma unroll
  for (int i = 0; i < 4; ++i) {
    int r = ty + i * 8;
    out[(size_t)(c0 + r) * R + r0 + tx] = f2bf(tile[tx][r]);
  }
}

// --------------------------------------------------- V [B,H,T,D]->[B,H,D,T]
__global__ __launch_bounds__(256) void transpose_v(const ushort* __restrict__ Vin,
                                                   ushort* __restrict__ Vout) {
  __shared__ ushort tl[64][66];
  int bh = blockIdx.y, t0 = blockIdx.x * 64;
  const ushort* src = Vin + (size_t)bh * Ts * Dd;
  ushort* dst = Vout + (size_t)bh * Dd * Ts;
  int tid = threadIdx.x;
#pragma unroll
  for (int it = 0; it < 2; ++it) {
    int idx = it * 256 + tid;
    int r = idx >> 3, c8 = idx & 7;
    u4us v; v.v = *reinterpret_cast<const uint4*>(src + (size_t)(t0 + r) * Dd + c8 * 8);
#pragma unroll
    for (int j = 0; j < 8; ++j) tl[r][c8 * 8 + j] = v.us[j];
  }
  __syncthreads();
#pragma unroll
  for (int it = 0; it < 2; ++it) {
    int idx = it * 256 + tid;
    int drow = idx >> 3, c8 = idx & 7;
    u4us o;
#pragma unroll
    for (int j = 0; j < 8; ++j) o.us[j] = tl[c8 * 8 + j][drow];
    *reinterpret_cast<uint4*>(dst + (size_t)drow * Ts + t0 + c8 * 8) = o.v;
  }
}

// ------------------------------------------------------------------- GEMM
// A[M,K] bf16 row-major, Bt[N,K] bf16 row-major (B transposed).
// EPI 0: C fp32 [M,N].  EPI 1: scatter columns to Q/K/V [B,H,T,D] bf16.
template <int EPI>
__global__ __launch_bounds__(256) void gemm_bt(const ushort* __restrict__ A,
                                               const ushort* __restrict__ Bt,
                                               int M, int N, int K,
                                               float* __restrict__ Cf,
                                               ushort* __restrict__ Qb,
                                               ushort* __restrict__ Kb,
                                               ushort* __restrict__ Vb) {
  __shared__ ushort Al[128 * 64];
  __shared__ ushort Bl[128 * 64];
  const int tid = threadIdx.x;
  const int lane = tid & 63, wid = tid >> 6;
  const int g = lane >> 4, l15 = lane & 15;
  const int wr = wid >> 1, wc = wid & 1;
  const int m0 = blockIdx.y * 128, n0 = blockIdx.x * 128;

  f32x4 acc[4][4];
#pragma unroll
  for (int i = 0; i < 4; ++i)
#pragma unroll
    for (int j = 0; j < 4; ++j) acc[i][j] = f32x4{0.f, 0.f, 0.f, 0.f};

  const int nkt = K >> 6;
  for (int kt = 0; kt < nkt; ++kt) {
#pragma unroll
    for (int it = 0; it < 4; ++it) {
      int chunk = it * 256 + tid;     // 0..1023
      int row = chunk >> 3, c16 = chunk & 7;
      uint4 va = *reinterpret_cast<const uint4*>(A + (size_t)(m0 + row) * K + kt * 64 + c16 * 8);
      lds_st128(Al, row, c16, va);
      uint4 vb = *reinterpret_cast<const uint4*>(Bt + (size_t)(n0 + row) * K + kt * 64 + c16 * 8);
      lds_st128(Bl, row, c16, vb);
    }
    __syncthreads();
#pragma unroll
    for (int ks = 0; ks < 2; ++ks) {
      frag_u af[4], bfr[4];
#pragma unroll
      for (int i = 0; i < 4; ++i) {
        ld_frag(af[i], Al, wr * 64 + i * 16 + l15, ks, g);
        ld_frag(bfr[i], Bl, wc * 64 + i * 16 + l15, ks, g);
      }
#pragma unroll
      for (int i = 0; i < 4; ++i)
#pragma unroll
        for (int j = 0; j < 4; ++j)
          acc[i][j] = __builtin_amdgcn_mfma_f32_16x16x32_bf16(af[i].f, bfr[j].f,
                                                              acc[i][j], 0, 0, 0);
    }
    __syncthreads();
  }

#pragma unroll
  for (int i = 0; i < 4; ++i)
#pragma unroll
    for (int j = 0; j < 4; ++j) {
      int mrow = m0 + wr * 64 + i * 16 + 4 * g;
      int ncol = n0 + wc * 64 + j * 16 + l15;
#pragma unroll
      for (int r = 0; r < 4; ++r) {
        float v = acc[i][j][r];
        int m = mrow + r;
        if (EPI == 0) {
          Cf[(size_t)m * N + ncol] = v;
        } else {
          int which = ncol >> 10, c = ncol & 1023;
          int hd = c >> 6, d = c & 63;
          int b = m >> 11, t = m & 2047;
          size_t idx = (((size_t)(b * Hh + hd)) * Ts + t) * Dd + d;
          ushort bv = f2bf(v);
          ushort* dst = (which == 0) ? Qb : (which == 1) ? Kb : Vb;
          dst[idx] = bv;
        }
      }
    }
}

// --------------------------------------------------------------- attention
// Q,K: [B*H, T, D] bf16; VT: [B*H, D, T] bf16; mask: [B, T] fp32 additive.
// Out: Y [B, T, C] bf16.
__global__ __launch_bounds__(256) void attn_kernel(const ushort* __restrict__ Qb,
                                                   const ushort* __restrict__ Kb,
                                                   const ushort* __restrict__ VTb,
                                                   const float* __restrict__ mask,
                                                   ushort* __restrict__ Yb) {
  __shared__ ushort Klds[64 * 64];
  __shared__ ushort Vlds[64 * 64];
  __shared__ ushort Plds[4][16 * 64];
  __shared__ float mlds[64];

  const int tid = threadIdx.x;
  const int lane = tid & 63, wid = tid >> 6;
  const int g = lane >> 4, l15 = lane & 15;
  const int bh = blockIdx.y;
  const int b = bh >> 4, h = bh & 15;
  const int qt = blockIdx.x;

  const ushort* Qh = Qb + (size_t)bh * Ts * Dd;
  const ushort* Kh = Kb + (size_t)bh * Ts * Dd;
  const ushort* Vh = VTb + (size_t)bh * Dd * Ts;

  // Q fragments for this wave's 16 q-rows, kept in registers all kernel
  frag_u aq[2];
  {
    int qrow = qt * 64 + wid * 16 + l15;
    const ushort* qp = Qh + (size_t)qrow * Dd;
#pragma unroll
    for (int ks = 0; ks < 2; ++ks) {
      aq[ks].u2[0] = *reinterpret_cast<const uint2*>(qp + ks * 32 + 4 * g);
      aq[ks].u2[1] = *reinterpret_cast<const uint2*>(qp + ks * 32 + 16 + 4 * g);
    }
  }

  float mprev[4], lsum[4];
  f32x4 acc[4];
#pragma unroll
  for (int r = 0; r < 4; ++r) { mprev[r] = -1e30f; lsum[r] = 0.f; }
#pragma unroll
  for (int dt = 0; dt < 4; ++dt) acc[dt] = f32x4{0.f, 0.f, 0.f, 0.f};

  for (int kt = 0; kt < Ts / 64; ++kt) {
#pragma unroll
    for (int it = 0; it < 2; ++it) {
      int idx = it * 256 + tid;     // 0..511
      int row = idx >> 3, c16 = idx & 7;
      uint4 kv = *reinterpret_cast<const uint4*>(Kh + (size_t)(kt * 64 + row) * Dd + c16 * 8);
      lds_st128(Klds, row, c16, kv);
      uint4 vv = *reinterpret_cast<const uint4*>(Vh + (size_t)row * Ts + kt * 64 + c16 * 8);
      lds_st128(Vlds, row, c16, vv);
    }
    if (tid < 64) mlds[tid] = mask[(size_t)b * Ts + kt * 64 + tid];
    __syncthreads();

    // S = Q K^T * scale + mask     (S tile: rows=q, cols=key)
    f32x4 s[4];
#pragma unroll
    for (int n = 0; n < 4; ++n) {
      f32x4 sv = f32x4{0.f, 0.f, 0.f, 0.f};
#pragma unroll
      for (int ks = 0; ks < 2; ++ks) {
        frag_u bk;
        ld_frag(bk, Klds, n * 16 + l15, ks, g);
        sv = __builtin_amdgcn_mfma_f32_16x16x32_bf16(aq[ks].f, bk.f, sv, 0, 0, 0);
      }
      float mv = mlds[n * 16 + l15];
#pragma unroll
      for (int r = 0; r < 4; ++r) sv[r] = sv[r] * 0.125f + mv;
      s[n] = sv;
    }

    // online softmax: row r of this lane-group is q = 4*g + r
    float corr[4];
#pragma unroll
    for (int r = 0; r < 4; ++r) {
      float tmax = fmaxf(fmaxf(s[0][r], s[1][r]), fmaxf(s[2][r], s[3][r]));
#pragma unroll
      for (int off = 1; off < 16; off <<= 1)
        tmax = fmaxf(tmax, __shfl_xor(tmax, off, 64));
      float mnew = fmaxf(mprev[r], tmax);
      corr[r] = __expf(mprev[r] - mnew);
      mprev[r] = mnew;
    }
    float psum[4] = {0.f, 0.f, 0.f, 0.f};
#pragma unroll
    for (int n = 0; n < 4; ++n) {
#pragma unroll
      for (int r = 0; r < 4; ++r) {
        float p = __expf(s[n][r] - mprev[r]);
        psum[r] += p;
        lds_st16(Plds[wid], 4 * g + r, n * 16 + l15, f2bf(p));
      }
    }
#pragma unroll
    for (int r = 0; r < 4; ++r) {
      float t = psum[r];
#pragma unroll
      for (int off = 1; off < 16; off <<= 1) t += __shfl_xor(t, off, 64);
      lsum[r] = lsum[r] * corr[r] + t;
    }
#pragma unroll
    for (int dt = 0; dt < 4; ++dt)
#pragma unroll
      for (int r = 0; r < 4; ++r) acc[dt][r] *= corr[r];

    // PV: acc[dt] += P (16q x 64key) * V (64key x 64d)
#pragma unroll
    for (int ks = 0; ks < 2; ++ks) {
      frag_u pa;
      ld_frag(pa, Plds[wid], l15, ks, g);
#pragma unroll
      for (int dt = 0; dt < 4; ++dt) {
        frag_u bv;
        ld_frag(bv, Vlds, dt * 16 + l15, ks, g);
        acc[dt] = __builtin_amdgcn_mfma_f32_16x16x32_bf16(pa.f, bv.f, acc[dt], 0, 0, 0);
      }
    }
    __syncthreads();
  }

  // epilogue: y = acc / lsum -> Y[b][t][h*64 + d]
  {
    int trow0 = qt * 64 + wid * 16 + 4 * g;
#pragma unroll
    for (int r = 0; r < 4; ++r) {
      float inv = 1.0f / lsum[r];
      int t = trow0 + r;
      size_t base = ((size_t)(b * Ts + t)) * Cc + h * Dd;
#pragma unroll
      for (int dt = 0; dt < 4; ++dt)
        Yb[base + dt * 16 + l15] = f2bf(acc[dt][r] * inv);
    }
  }
}

// ------------------------------------------------------------------ launch
extern "C" void kernel_launch(void* const* d_in, const int* in_sizes, int n_in,
                              void* d_out, int out_size, void* d_ws, size_t ws_size,
                              hipStream_t stream) {
  const float* h    = (const float*)d_in[0];
  const float* mask = (const float*)d_in[1];
  const float* wa   = (const float*)d_in[2];   // [1024, 3072]
  const float* wp   = (const float*)d_in[3];   // [1024, 1024]
  float* out = (float*)d_out;

  char* ws = (char*)d_ws;
  ushort* hbf     = (ushort*)(ws);                    // 16 MiB (reused as Ybf)
  ushort* wattn_t = (ushort*)(ws + (16u << 20));      // 6 MiB
  ushort* wproj_t = (ushort*)(ws + (22u << 20));      // 2 MiB
  ushort* Qb      = (ushort*)(ws + (24u << 20));      // 16 MiB
  ushort* Kb      = (ushort*)(ws + (40u << 20));      // 16 MiB
  ushort* Vtmp    = (ushort*)(ws + (56u << 20));      // 16 MiB
  ushort* VTb     = (ushort*)(ws + (72u << 20));      // 16 MiB  (end: 88 MiB)
  ushort* Ybf = hbf;

  cvt_kernel<<<2048, 256, 0, stream>>>(h, hbf, (Mm * Cc) / 4);
  transpose_cvt<<<dim3(3 * Cc / 32, Cc / 32), 256, 0, stream>>>(wa, wattn_t, Cc, 3 * Cc);
  transpose_cvt<<<dim3(Cc / 32, Cc / 32), 256, 0, stream>>>(wp, wproj_t, Cc, Cc);

  gemm_bt<1><<<dim3(3 * Cc / 128, Mm / 128), 256, 0, stream>>>(
      hbf, wattn_t, Mm, 3 * Cc, Cc, nullptr, Qb, Kb, Vtmp);

  transpose_v<<<dim3(Ts / 64, Bb * Hh), 256, 0, stream>>>(Vtmp, VTb);

  attn_kernel<<<dim3(Ts / 64, Bb * Hh), 256, 0, stream>>>(Qb, Kb, VTb, mask, Ybf);

  gemm_bt<0><<<dim3(Cc / 128, Mm / 128), 256, 0, stream>>>(
      Ybf, wproj_t, Mm, Cc, Cc, out, nullptr, nullptr, nullptr);
}

// Round 2
// 289.587 us; speedup vs baseline: 1.2472x; 1.2472x over previous
//
#include <hip/hip_runtime.h>
#include <hip/hip_bf16.h>

#define DEV static __device__ __forceinline__

typedef __attribute__((ext_vector_type(4))) float f32x4;
typedef __attribute__((ext_vector_type(8))) short bf16x8;

constexpr int Bb = 4, Ts = 2048, Cc = 1024, Hh = 16, Dd = 64;
constexpr int Mm = Bb * Ts;   // 8192

union frag_u {
  bf16x8 f;
  uint2  u2[2];
  ushort us[8];
  uint4  u4;
};

DEV ushort f2bf(float x) {
  union { float f; unsigned u; } v; v.f = x;
  unsigned r = v.u + 0x7FFFu + ((v.u >> 16) & 1u);
  return (ushort)(r >> 16);
}

DEV ushort f2bf_hw(float x) {   // compiler fuses pairs into v_cvt_pk_bf16_f32
  union { __hip_bfloat16 b; ushort u; } cv;
  cv.b = __float2bfloat16(x);
  return cv.u;
}

// ---- swizzled LDS helpers: tile rows are 64 bf16 = 128 bytes; XOR 16B-chunk
// index with (row&7) to kill the row-major same-bank conflict (G4).
DEV int swz_off(int row, int bytecol) {
  return row * 128 + ((((bytecol >> 4) ^ (row & 7)) << 4) | (bytecol & 15));
}
DEV uint2 lds_ld64(const ushort* lds, int row, int colbf) {
  int off = swz_off(row, colbf << 1);
  return *reinterpret_cast<const uint2*>(reinterpret_cast<const char*>(lds) + off);
}
DEV void lds_st128(ushort* lds, int row, int c16, uint4 v) {
  int off = row * 128 + ((c16 ^ (row & 7)) << 4);
  *reinterpret_cast<uint4*>(reinterpret_cast<char*>(lds) + off) = v;
}

// load one A/B fragment (two K=16 halves) from a swizzled [rows][64] tile
DEV void ld_frag(frag_u& fr, const ushort* lds, int row, int ks, int g) {
  fr.u2[0] = lds_ld64(lds, row, ks * 32 + 4 * g);
  fr.u2[1] = lds_ld64(lds, row, ks * 32 + 16 + 4 * g);
}

// ---------------------------------------------------------------- convert h
__global__ __launch_bounds__(256) void cvt_kernel(const float* __restrict__ in,
                                                  ushort* __restrict__ out, int n4) {
  for (int i = blockIdx.x * blockDim.x + threadIdx.x; i < n4;
       i += gridDim.x * blockDim.x) {
    float4 v = reinterpret_cast<const float4*>(in)[i];
    ushort4 o;
    o.x = f2bf(v.x); o.y = f2bf(v.y); o.z = f2bf(v.z); o.w = f2bf(v.w);
    reinterpret_cast<ushort4*>(out)[i] = o;
  }
}

// ------------------------------------------- transpose+convert weight to bf16
// in[R][Ccols] fp32 -> out[Ccols][R] bf16
__global__ __launch_bounds__(256) void transpose_cvt(const float* __restrict__ in,
                                                     ushort* __restrict__ out,
                                                     int R, int Ccols) {
  __shared__ float tile[32][33];
  int c0 = blockIdx.x * 32, r0 = blockIdx.y * 32;
  int tx = threadIdx.x & 31, ty = threadIdx.x >> 5;
#pragma unroll
  for (int i = 0; i < 4; ++i) {
    int r = ty + i * 8;
    tile[r][tx] = in[(size_t)(r0 + r) * Ccols + c0 + tx];
  }
  __syncthreads();
#pragma unroll
  for (int i = 0; i < 4; ++i) {
    int r = ty + i * 8;
    out[(size_t)(c0 + r) * R + r0 + tx] = f2bf(tile[tx][r]);
  }
}

// ------------------------------------------------------------------- GEMM
// A[M,K] bf16 row-major, Bt[N,K] bf16 row-major (B transposed).
// EPI 0: C fp32 [M,N].  EPI 1: scatter Q,K -> [B,H,T,D] bf16, V -> [B,H,D,T].
template <int EPI>
__global__ __launch_bounds__(256) void gemm_bt(const ushort* __restrict__ A,
                                               const ushort* __restrict__ Bt,
                                               int M, int N, int K,
                                               float* __restrict__ Cf,
                                               ushort* __restrict__ Qb,
                                               ushort* __restrict__ Kb,
                                               ushort* __restrict__ Vb) {
  __shared__ ushort Al[128 * 64];
  __shared__ ushort Bl[128 * 64];
  const int tid = threadIdx.x;
  const int lane = tid & 63, wid = tid >> 6;
  const int g = lane >> 4, l15 = lane & 15;
  const int wr = wid >> 1, wc = wid & 1;
  const int m0 = blockIdx.y * 128, n0 = blockIdx.x * 128;

  f32x4 acc[4][4];
#pragma unroll
  for (int i = 0; i < 4; ++i)
#pragma unroll
    for (int j = 0; j < 4; ++j) acc[i][j] = f32x4{0.f, 0.f, 0.f, 0.f};

  const int nkt = K >> 6;
  for (int kt = 0; kt < nkt; ++kt) {
#pragma unroll
    for (int it = 0; it < 4; ++it) {
      int chunk = it * 256 + tid;     // 0..1023
      int row = chunk >> 3, c16 = chunk & 7;
      uint4 va = *reinterpret_cast<const uint4*>(A + (size_t)(m0 + row) * K + kt * 64 + c16 * 8);
      lds_st128(Al, row, c16, va);
      uint4 vb = *reinterpret_cast<const uint4*>(Bt + (size_t)(n0 + row) * K + kt * 64 + c16 * 8);
      lds_st128(Bl, row, c16, vb);
    }
    __syncthreads();
#pragma unroll
    for (int ks = 0; ks < 2; ++ks) {
      frag_u af[4], bfr[4];
#pragma unroll
      for (int i = 0; i < 4; ++i) {
        ld_frag(af[i], Al, wr * 64 + i * 16 + l15, ks, g);
        ld_frag(bfr[i], Bl, wc * 64 + i * 16 + l15, ks, g);
      }
#pragma unroll
      for (int i = 0; i < 4; ++i)
#pragma unroll
        for (int j = 0; j < 4; ++j)
          acc[i][j] = __builtin_amdgcn_mfma_f32_16x16x32_bf16(af[i].f, bfr[j].f,
                                                              acc[i][j], 0, 0, 0);
    }
    __syncthreads();
  }

#pragma unroll
  for (int i = 0; i < 4; ++i)
#pragma unroll
    for (int j = 0; j < 4; ++j) {
      int mrow = m0 + wr * 64 + i * 16 + 4 * g;
      int ncol = n0 + wc * 64 + j * 16 + l15;
#pragma unroll
      for (int r = 0; r < 4; ++r) {
        float v = acc[i][j][r];
        int m = mrow + r;
        if (EPI == 0) {
          Cf[(size_t)m * N + ncol] = v;
        } else {
          int which = ncol >> 10, c = ncol & 1023;
          int hd = c >> 6, d = c & 63;
          int b = m >> 11, t = m & 2047;
          size_t idx;
          if (which == 2)  // V stored transposed: [B,H,D,T]
            idx = (((size_t)(b * Hh + hd)) * Dd + d) * Ts + t;
          else
            idx = (((size_t)(b * Hh + hd)) * Ts + t) * Dd + d;
          ushort bv = f2bf(v);
          ushort* dst = (which == 0) ? Qb : (which == 1) ? Kb : Vb;
          dst[idx] = bv;
        }
      }
    }
}

// --------------------------------------------------------------- attention
// Q,K: [B*H, T, D] bf16; VT: [B*H, D, T] bf16; mask: [B, T] fp32 additive.
// Out: Y [B, T, C] bf16.
// Swapped QK^T (mfma(K,Q) -> S^T): each lane owns ONE q-row (q = l15 within
// wave tile); its 16 score regs are already in PV's A-fragment layout, so P
// never touches LDS. Softmax in exp2 domain; defer-max (T13, THR=8);
// double-buffered K/V with issue-early/commit-late staging (T14).
__global__ __launch_bounds__(256) void attn_kernel(const ushort* __restrict__ Qb,
                                                   const ushort* __restrict__ Kb,
                                                   const ushort* __restrict__ VTb,
                                                   const float* __restrict__ mask,
                                                   ushort* __restrict__ Yb) {
  __shared__ ushort Klds[2][64 * 64];
  __shared__ ushort Vlds[2][64 * 64];
  __shared__ float mlds[2][64];

  const int tid = threadIdx.x;
  const int lane = tid & 63, wid = tid >> 6;
  const int g = lane >> 4, l15 = lane & 15;
  const int bh = blockIdx.x;            // x = head: same head -> same XCD (L2)
  const int b = bh >> 4, h = bh & 15;
  const int qt = blockIdx.y;

  const ushort* Qh = Qb + (size_t)bh * Ts * Dd;
  const ushort* Kh = Kb + (size_t)bh * Ts * Dd;
  const ushort* Vh = VTb + (size_t)bh * Dd * Ts;
  const float* mrow = mask + (size_t)b * Ts;

  const int srow0 = tid >> 3, sc16 = tid & 7;   // staging coords (rows 0..31)
  const int srow1 = srow0 + 32;                 //                (rows 32..63)

  // Q fragments (PV/QK B-operand), q = qt*64 + wid*16 + l15, in regs all kernel
  frag_u aq[2];
  {
    const ushort* qp = Qh + (size_t)(qt * 64 + wid * 16 + l15) * Dd;
#pragma unroll
    for (int ks = 0; ks < 2; ++ks) {
      aq[ks].u2[0] = *reinterpret_cast<const uint2*>(qp + ks * 32 + 4 * g);
      aq[ks].u2[1] = *reinterpret_cast<const uint2*>(qp + ks * 32 + 16 + 4 * g);
    }
  }

  float mprev = -1e30f, lsum = 0.f;   // per-lane state for q-row = l15
  f32x4 acc[4];
#pragma unroll
  for (int dt = 0; dt < 4; ++dt) acc[dt] = f32x4{0.f, 0.f, 0.f, 0.f};

  uint4 kreg0, kreg1, vreg0, vreg1;
  float mreg = 0.f;
  const float LOG2E = 1.44269504f;

#define ISSUE(kt)                                                               \
  kreg0 = *reinterpret_cast<const uint4*>(Kh + (size_t)((kt) * 64 + srow0) * Dd + sc16 * 8); \
  kreg1 = *reinterpret_cast<const uint4*>(Kh + (size_t)((kt) * 64 + srow1) * Dd + sc16 * 8); \
  vreg0 = *reinterpret_cast<const uint4*>(Vh + (size_t)srow0 * Ts + (kt) * 64 + sc16 * 8);   \
  vreg1 = *reinterpret_cast<const uint4*>(Vh + (size_t)srow1 * Ts + (kt) * 64 + sc16 * 8);   \
  if (tid < 64) mreg = mrow[(kt) * 64 + tid] * LOG2E;

#define COMMIT(buf)                                                             \
  lds_st128(Klds[buf], srow0, sc16, kreg0);                                     \
  lds_st128(Klds[buf], srow1, sc16, kreg1);                                     \
  lds_st128(Vlds[buf], srow0, sc16, vreg0);                                     \
  lds_st128(Vlds[buf], srow1, sc16, vreg1);                                     \
  if (tid < 64) mlds[buf][tid] = mreg;

  ISSUE(0);
  COMMIT(0);
  __syncthreads();

  const float SC = 0.125f * LOG2E;    // scale folded with log2(e)
  const int NT = Ts / 64;
  for (int kt = 0; kt < NT; ++kt) {
    const int cur = kt & 1;
    const bool more = (kt + 1 < NT);
    if (more) { ISSUE(kt + 1); }      // issue-early: HBM hides under compute

    // S^T = K Q^T: s[n][r] = score(key = n*16+4g+r, q = l15) in log2 domain
    f32x4 s[4];
#pragma unroll
    for (int n = 0; n < 4; ++n) {
      f32x4 sv = f32x4{0.f, 0.f, 0.f, 0.f};
#pragma unroll
      for (int ks = 0; ks < 2; ++ks) {
        frag_u bk;
        ld_frag(bk, Klds[cur], n * 16 + l15, ks, g);
        sv = __builtin_amdgcn_mfma_f32_16x16x32_bf16(bk.f, aq[ks].f, sv, 0, 0, 0);
      }
      f32x4 mk = *reinterpret_cast<const f32x4*>(&mlds[cur][n * 16 + 4 * g]);
#pragma unroll
      for (int r = 0; r < 4; ++r) sv[r] = sv[r] * SC + mk[r];
      s[n] = sv;
    }

    // online softmax, defer-max: rescale only if max grew by > 8 (2^8 headroom)
    float tmax = fmaxf(fmaxf(s[0][0], s[0][1]), fmaxf(s[0][2], s[0][3]));
#pragma unroll
    for (int n = 1; n < 4; ++n)
      tmax = fmaxf(tmax, fmaxf(fmaxf(s[n][0], s[n][1]), fmaxf(s[n][2], s[n][3])));
    tmax = fmaxf(tmax, __shfl_xor(tmax, 16, 64));
    tmax = fmaxf(tmax, __shfl_xor(tmax, 32, 64));
    if (__any(tmax > mprev + 8.f)) {
      float mnew = fmaxf(mprev, tmax);
      float corr = __builtin_amdgcn_exp2f(mprev - mnew);
      mprev = mnew;
      lsum *= corr;
      float cq[4];
#pragma unroll
      for (int r = 0; r < 4; ++r) cq[r] = __shfl(corr, 4 * g + r, 64);
#pragma unroll
      for (int dt = 0; dt < 4; ++dt)
#pragma unroll
        for (int r = 0; r < 4; ++r) acc[dt][r] *= cq[r];
    }

    // P = 2^(s - mprev); registers land directly in PV A-fragment layout
    frag_u pa[2];
    float psum = 0.f;
#pragma unroll
    for (int n = 0; n < 4; ++n) {
#pragma unroll
      for (int r = 0; r < 4; ++r) {
        float p = __builtin_amdgcn_exp2f(s[n][r] - mprev);
        psum += p;
        pa[n >> 1].us[(n & 1) * 4 + r] = f2bf_hw(p);
      }
    }
    psum += __shfl_xor(psum, 16, 64);
    psum += __shfl_xor(psum, 32, 64);
    lsum += psum;

    // PV: acc[dt] += P(16q x 64k) * V(64k x 64d)
#pragma unroll
    for (int ks = 0; ks < 2; ++ks) {
#pragma unroll
      for (int dt = 0; dt < 4; ++dt) {
        frag_u bv;
        ld_frag(bv, Vlds[cur], dt * 16 + l15, ks, g);
        acc[dt] = __builtin_amdgcn_mfma_f32_16x16x32_bf16(pa[ks].f, bv.f, acc[dt], 0, 0, 0);
      }
    }

    if (more) { COMMIT(cur ^ 1); }    // commit-late into the idle buffer
    __syncthreads();
  }
#undef ISSUE
#undef COMMIT

  // epilogue: y = acc / lsum -> Y[b][t][h*64 + d]
  float lq[4];
#pragma unroll
  for (int r = 0; r < 4; ++r) lq[r] = __shfl(lsum, 4 * g + r, 64);
  const int trow0 = qt * 64 + wid * 16 + 4 * g;
#pragma unroll
  for (int r = 0; r < 4; ++r) {
    float inv = 1.0f / lq[r];
    size_t base = ((size_t)(b * Ts + trow0 + r)) * Cc + h * Dd;
#pragma unroll
    for (int dt = 0; dt < 4; ++dt)
      Yb[base + dt * 16 + l15] = f2bf(acc[dt][r] * inv);
  }
}

// ------------------------------------------------------------------ launch
extern "C" void kernel_launch(void* const* d_in, const int* in_sizes, int n_in,
                              void* d_out, int out_size, void* d_ws, size_t ws_size,
                              hipStream_t stream) {
  const float* h    = (const float*)d_in[0];
  const float* mask = (const float*)d_in[1];
  const float* wa   = (const float*)d_in[2];   // [1024, 3072]
  const float* wp   = (const float*)d_in[3];   // [1024, 1024]
  float* out = (float*)d_out;

  char* ws = (char*)d_ws;
  ushort* hbf     = (ushort*)(ws);                    // 16 MiB (reused as Ybf)
  ushort* wattn_t = (ushort*)(ws + (16u << 20));      // 6 MiB
  ushort* wproj_t = (ushort*)(ws + (22u << 20));      // 2 MiB
  ushort* Qb      = (ushort*)(ws + (24u << 20));      // 16 MiB
  ushort* Kb      = (ushort*)(ws + (40u << 20));      // 16 MiB
  ushort* VTb     = (ushort*)(ws + (56u << 20));      // 16 MiB (end: 72 MiB)
  ushort* Ybf = hbf;

  cvt_kernel<<<2048, 256, 0, stream>>>(h, hbf, (Mm * Cc) / 4);
  transpose_cvt<<<dim3(3 * Cc / 32, Cc / 32), 256, 0, stream>>>(wa, wattn_t, Cc, 3 * Cc);
  transpose_cvt<<<dim3(Cc / 32, Cc / 32), 256, 0, stream>>>(wp, wproj_t, Cc, Cc);

  gemm_bt<1><<<dim3(3 * Cc / 128, Mm / 128), 256, 0, stream>>>(
      hbf, wattn_t, Mm, 3 * Cc, Cc, nullptr, Qb, Kb, VTb);

  attn_kernel<<<dim3(Bb * Hh, Ts / 64), 256, 0, stream>>>(Qb, Kb, VTb, mask, Ybf);

  gemm_bt<0><<<dim3(Cc / 128, Mm / 128), 256, 0, stream>>>(
      Ybf, wproj_t, Mm, Cc, Cc, out, nullptr, nullptr, nullptr);
}

// Round 3
// 222.202 us; speedup vs baseline: 1.6254x; 1.3033x over previous
//
#include <hip/hip_runtime.h>
#include <hip/hip_bf16.h>

#define DEV static __device__ __forceinline__

typedef __attribute__((ext_vector_type(4))) float f32x4;
typedef __attribute__((ext_vector_type(8))) short bf16x8;

constexpr int Bb = 4, Ts = 2048, Cc = 1024, Hh = 16, Dd = 64;
constexpr int Mm = Bb * Ts;   // 8192
constexpr float SCQ = 0.18033688f;   // 0.125 * log2(e), folded into Q

union frag_u {
  bf16x8 f;
  uint2  u2[2];
  ushort us[8];
  uint4  u4;
};

DEV ushort f2bf(float x) {
  union { float f; unsigned u; } v; v.f = x;
  unsigned r = v.u + 0x7FFFu + ((v.u >> 16) & 1u);
  return (ushort)(r >> 16);
}

DEV ushort f2bf_hw(float x) {   // compiler fuses pairs into v_cvt_pk_bf16_f32
  union { __hip_bfloat16 b; ushort u; } cv;
  cv.b = __float2bfloat16(x);
  return cv.u;
}

// ---- swizzled LDS tile: rows are 64 bf16 = 128 bytes = 8 chunks of 16B.
// chunk index XOR (row&7) kills the row-major same-bank conflict (G4).
DEV void lds_st128(ushort* lds, int row, int c16, uint4 v) {
  int off = row * 128 + ((c16 ^ (row & 7)) << 4);
  *reinterpret_cast<uint4*>(reinterpret_cast<char*>(lds) + off) = v;
}
// contiguous-pi fragment read: one b128 = 8 bf16 at chunk (4*ks+g)
DEV void ld_frag16(frag_u& fr, const ushort* lds, int row, int chunk) {
  int off = row * 128 + ((chunk ^ (row & 7)) << 4);
  fr.u4 = *reinterpret_cast<const uint4*>(reinterpret_cast<const char*>(lds) + off);
}
// 8B store at permuted column p (p multiple of 4) within swizzled row
DEV void lds_st64p(ushort* lds, int row, int p, uint2 v) {
  int off = row * 128 + ((((p >> 3) ^ (row & 7)) << 4) | ((2 * p) & 15));
  *reinterpret_cast<uint2*>(reinterpret_cast<char*>(lds) + off) = v;
}

// ---------------------------------------------------------------- convert h
__global__ __launch_bounds__(256) void cvt_kernel(const float* __restrict__ in,
                                                  ushort* __restrict__ out, int n4) {
  for (int i = blockIdx.x * blockDim.x + threadIdx.x; i < n4;
       i += gridDim.x * blockDim.x) {
    float4 v = reinterpret_cast<const float4*>(in)[i];
    ushort4 o;
    o.x = f2bf(v.x); o.y = f2bf(v.y); o.z = f2bf(v.z); o.w = f2bf(v.w);
    reinterpret_cast<ushort4*>(out)[i] = o;
  }
}

// ------------------------------------------- transpose+convert weight to bf16
__global__ __launch_bounds__(256) void transpose_cvt(const float* __restrict__ in,
                                                     ushort* __restrict__ out,
                                                     int R, int Ccols) {
  __shared__ float tile[32][33];
  int c0 = blockIdx.x * 32, r0 = blockIdx.y * 32;
  int tx = threadIdx.x & 31, ty = threadIdx.x >> 5;
#pragma unroll
  for (int i = 0; i < 4; ++i) {
    int r = ty + i * 8;
    tile[r][tx] = in[(size_t)(r0 + r) * Ccols + c0 + tx];
  }
  __syncthreads();
#pragma unroll
  for (int i = 0; i < 4; ++i) {
    int r = ty + i * 8;
    out[(size_t)(c0 + r) * R + r0 + tx] = f2bf(tile[tx][r]);
  }
}

// ------------------------------------------------------------------- GEMM
// A[M,K] bf16 row-major, Bt[N,K] bf16 row-major (B transposed).
// EPI 0: C fp32 [M,N].
// EPI 1: Q (scaled by SCQ), K -> [B,H,T,D] bf16; V (scaled by exp(mask)) -> [B,H,D,T].
template <int EPI>
__global__ __launch_bounds__(256) void gemm_bt(const ushort* __restrict__ A,
                                               const ushort* __restrict__ Bt,
                                               int M, int N, int K,
                                               float* __restrict__ Cf,
                                               ushort* __restrict__ Qb,
                                               ushort* __restrict__ Kb,
                                               ushort* __restrict__ Vb,
                                               const float* __restrict__ maskp) {
  __shared__ ushort Al[128 * 64];
  __shared__ ushort Bl[128 * 64];
  const int tid = threadIdx.x;
  const int lane = tid & 63, wid = tid >> 6;
  const int g = lane >> 4, l15 = lane & 15;
  const int wr = wid >> 1, wc = wid & 1;
  const int m0 = blockIdx.y * 128, n0 = blockIdx.x * 128;

  f32x4 acc[4][4];
#pragma unroll
  for (int i = 0; i < 4; ++i)
#pragma unroll
    for (int j = 0; j < 4; ++j) acc[i][j] = f32x4{0.f, 0.f, 0.f, 0.f};

  const int nkt = K >> 6;
  for (int kt = 0; kt < nkt; ++kt) {
#pragma unroll
    for (int it = 0; it < 4; ++it) {
      int chunk = it * 256 + tid;     // 0..1023
      int row = chunk >> 3, c16 = chunk & 7;
      uint4 va = *reinterpret_cast<const uint4*>(A + (size_t)(m0 + row) * K + kt * 64 + c16 * 8);
      lds_st128(Al, row, c16, va);
      uint4 vb = *reinterpret_cast<const uint4*>(Bt + (size_t)(n0 + row) * K + kt * 64 + c16 * 8);
      lds_st128(Bl, row, c16, vb);
    }
    __syncthreads();
#pragma unroll
    for (int ks = 0; ks < 2; ++ks) {
      frag_u af[4], bfr[4];
#pragma unroll
      for (int i = 0; i < 4; ++i) {
        ld_frag16(af[i], Al, wr * 64 + i * 16 + l15, 4 * ks + g);
        ld_frag16(bfr[i], Bl, wc * 64 + i * 16 + l15, 4 * ks + g);
      }
#pragma unroll
      for (int i = 0; i < 4; ++i)
#pragma unroll
        for (int j = 0; j < 4; ++j)
          acc[i][j] = __builtin_amdgcn_mfma_f32_16x16x32_bf16(af[i].f, bfr[j].f,
                                                              acc[i][j], 0, 0, 0);
    }
    __syncthreads();
  }

#pragma unroll
  for (int i = 0; i < 4; ++i)
#pragma unroll
    for (int j = 0; j < 4; ++j) {
      int mrow = m0 + wr * 64 + i * 16 + 4 * g;
      int ncol = n0 + wc * 64 + j * 16 + l15;
#pragma unroll
      for (int r = 0; r < 4; ++r) {
        float v = acc[i][j][r];
        int m = mrow + r;
        if (EPI == 0) {
          Cf[(size_t)m * N + ncol] = v;
        } else {
          int which = ncol >> 10, c = ncol & 1023;
          int hd = c >> 6, d = c & 63;
          int b = m >> 11, t = m & 2047;
          size_t idx;
          if (which == 2) {   // V: scaled by exp(mask), stored [B,H,D,T]
            v *= __expf(maskp[(size_t)b * Ts + t]);
            idx = (((size_t)(b * Hh + hd)) * Dd + d) * Ts + t;
          } else {
            if (which == 0) v *= SCQ;   // Q pre-scaled
            idx = (((size_t)(b * Hh + hd)) * Ts + t) * Dd + d;
          }
          ushort bv = f2bf(v);
          ushort* dst = (which == 0) ? Qb : (which == 1) ? Kb : Vb;
          dst[idx] = bv;
        }
      }
    }
}

// --------------------------------------------------------------- attention
// Q (pre-scaled), K: [B*H,T,D]; VT (mask-folded): [B*H,D,T]; out Y [B,T,C] bf16.
// 4 waves x 64 q-rows = 256 q/block. Swapped QK^T keeps P in registers; lsum
// via MFMA against w = exp(mask) column (same lane layout as acc -> no shfl).
__global__ __launch_bounds__(256, 2) void attn_kernel(const ushort* __restrict__ Qb,
                                                      const ushort* __restrict__ Kb,
                                                      const ushort* __restrict__ VTb,
                                                      const float* __restrict__ mask,
                                                      ushort* __restrict__ Yb) {
  __shared__ ushort Klds[2][64 * 64];
  __shared__ ushort Vlds[2][64 * 64];
  __shared__ ushort wlds[2][64];

  const int tid = threadIdx.x;
  const int lane = tid & 63, wid = tid >> 6;
  const int g = lane >> 4, l15 = lane & 15;
  const int bh = blockIdx.x;            // x = head: same head -> same XCD (L2)
  const int b = bh >> 4, h = bh & 15;
  const int qt = blockIdx.y;

  const ushort* Qh = Qb + (size_t)bh * Ts * Dd;
  const ushort* Kh = Kb + (size_t)bh * Ts * Dd;
  const ushort* Vh = VTb + (size_t)bh * Dd * Ts;
  const float* mrow = mask + (size_t)b * Ts;

  const int srow0 = tid >> 3, sc16 = tid & 7;   // staging coords
  const int srow1 = srow0 + 32;
  // V permuted-column base for old-pi contiguous reads
  const int vp0 = 32 * (sc16 >> 2) + 16 * (sc16 & 1) + 4 * ((sc16 >> 1) & 1);
  // w permuted index: key bits [ks][h][g][r] -> p bits [ks][g][h][r]
  const int wp = (tid & 32) | ((tid & 12) << 1) | ((tid & 16) >> 2) | (tid & 3);

  // Q fragments: 4 qsub x 2 ks, contiguous-pi (k-slot = ks*32 + 8g + j)
  frag_u aq[4][2];
#pragma unroll
  for (int qsub = 0; qsub < 4; ++qsub) {
    const ushort* qp = Qh + (size_t)(qt * 256 + wid * 64 + qsub * 16 + l15) * Dd;
#pragma unroll
    for (int ks = 0; ks < 2; ++ks)
      aq[qsub][ks].u4 = *reinterpret_cast<const uint4*>(qp + ks * 32 + 8 * g);
  }

  float mprev[4];
  f32x4 acc[4][4];    // [qsub][dt]: row q=4g+r, col d=dt*16+l15
  f32x4 lacc[4];      // lsum accumulator, same lane layout as acc rows
#pragma unroll
  for (int q = 0; q < 4; ++q) {
    mprev[q] = -1e30f;
    lacc[q] = f32x4{0.f, 0.f, 0.f, 0.f};
#pragma unroll
    for (int dt = 0; dt < 4; ++dt) acc[q][dt] = f32x4{0.f, 0.f, 0.f, 0.f};
  }

  uint4 kreg0, kreg1, vreg0, vreg1;
  float wreg = 0.f;

#define ISSUE(kt)                                                               \
  kreg0 = *reinterpret_cast<const uint4*>(Kh + (size_t)((kt) * 64 + srow0) * Dd + sc16 * 8); \
  kreg1 = *reinterpret_cast<const uint4*>(Kh + (size_t)((kt) * 64 + srow1) * Dd + sc16 * 8); \
  vreg0 = *reinterpret_cast<const uint4*>(Vh + (size_t)srow0 * Ts + (kt) * 64 + sc16 * 8);   \
  vreg1 = *reinterpret_cast<const uint4*>(Vh + (size_t)srow1 * Ts + (kt) * 64 + sc16 * 8);   \
  wreg = (tid < 64) ? __expf(mrow[(kt) * 64 + tid]) : 0.f;

#define COMMIT(buf)                                                             \
  lds_st128(Klds[buf], srow0, sc16, kreg0);                                     \
  lds_st128(Klds[buf], srow1, sc16, kreg1);                                     \
  lds_st64p(Vlds[buf], srow0, vp0, uint2{vreg0.x, vreg0.y});                    \
  lds_st64p(Vlds[buf], srow0, vp0 + 8, uint2{vreg0.z, vreg0.w});                \
  lds_st64p(Vlds[buf], srow1, vp0, uint2{vreg1.x, vreg1.y});                    \
  lds_st64p(Vlds[buf], srow1, vp0 + 8, uint2{vreg1.z, vreg1.w});                \
  if (tid < 64) wlds[buf][wp] = f2bf_hw(wreg);

  ISSUE(0);
  COMMIT(0);
  __syncthreads();

  const int NT = Ts / 64;
  for (int kt = 0; kt < NT; ++kt) {
    const int cur = kt & 1;
    const bool more = (kt + 1 < NT);

    // ---- QK^T (swapped): s[qsub][n][r] = score(key=n*16+4g+r, q=l15)
    f32x4 s[4][4];
#pragma unroll
    for (int q = 0; q < 4; ++q)
#pragma unroll
      for (int n = 0; n < 4; ++n) s[q][n] = f32x4{0.f, 0.f, 0.f, 0.f};
#pragma unroll
    for (int ks = 0; ks < 2; ++ks)
#pragma unroll
      for (int n = 0; n < 4; ++n) {
        frag_u bk;
        ld_frag16(bk, Klds[cur], n * 16 + l15, 4 * ks + g);
#pragma unroll
        for (int q = 0; q < 4; ++q)
          s[q][n] = __builtin_amdgcn_mfma_f32_16x16x32_bf16(bk.f, aq[q][ks].f,
                                                            s[q][n], 0, 0, 0);
      }

    if (more) { ISSUE(kt + 1); }   // hide HBM/L2 latency under softmax+PV

    // ---- online softmax per qsub (defer-max, exp2 domain)
    frag_u pa[4][2];
#pragma unroll
    for (int q = 0; q < 4; ++q) {
      float tmax = fmaxf(fmaxf(s[q][0][0], s[q][0][1]), fmaxf(s[q][0][2], s[q][0][3]));
#pragma unroll
      for (int n = 1; n < 4; ++n)
        tmax = fmaxf(tmax, fmaxf(fmaxf(s[q][n][0], s[q][n][1]),
                                 fmaxf(s[q][n][2], s[q][n][3])));
      tmax = fmaxf(tmax, __shfl_xor(tmax, 16, 64));
      tmax = fmaxf(tmax, __shfl_xor(tmax, 32, 64));
      if (__any(tmax > mprev[q] + 8.f)) {
        float mnew = fmaxf(mprev[q], tmax);
        float corr = __builtin_amdgcn_exp2f(mprev[q] - mnew);
        mprev[q] = mnew;
        float cq[4];
#pragma unroll
        for (int r = 0; r < 4; ++r) cq[r] = __shfl(corr, 4 * g + r, 64);
#pragma unroll
        for (int dt = 0; dt < 4; ++dt)
#pragma unroll
          for (int r = 0; r < 4; ++r) acc[q][dt][r] *= cq[r];
#pragma unroll
        for (int r = 0; r < 4; ++r) lacc[q][r] *= cq[r];
      }
#pragma unroll
      for (int n = 0; n < 4; ++n)
#pragma unroll
        for (int r = 0; r < 4; ++r) {
          float p = __builtin_amdgcn_exp2f(s[q][n][r] - mprev[q]);
          pa[q][n >> 1].us[(n & 1) * 4 + r] = f2bf_hw(p);
        }
    }

    // ---- lsum via MFMA: lacc += P * w  (w = exp(mask), all 16 cols equal)
    frag_u wf[2];
    wf[0].u4 = *reinterpret_cast<const uint4*>(&wlds[cur][8 * g]);
    wf[1].u4 = *reinterpret_cast<const uint4*>(&wlds[cur][32 + 8 * g]);
#pragma unroll
    for (int ks = 0; ks < 2; ++ks)
#pragma unroll
      for (int q = 0; q < 4; ++q)
        lacc[q] = __builtin_amdgcn_mfma_f32_16x16x32_bf16(pa[q][ks].f, wf[ks].f,
                                                          lacc[q], 0, 0, 0);

    // ---- PV: acc[q][dt] += P(16q x 64k) * V(64k x 64d)
#pragma unroll
    for (int ks = 0; ks < 2; ++ks)
#pragma unroll
      for (int dt = 0; dt < 4; ++dt) {
        frag_u bv;
        ld_frag16(bv, Vlds[cur], dt * 16 + l15, 4 * ks + g);
#pragma unroll
        for (int q = 0; q < 4; ++q)
          acc[q][dt] = __builtin_amdgcn_mfma_f32_16x16x32_bf16(pa[q][ks].f, bv.f,
                                                               acc[q][dt], 0, 0, 0);
      }

    if (more) { COMMIT(cur ^ 1); }
    __syncthreads();
  }
#undef ISSUE
#undef COMMIT

  // epilogue: y = acc / lsum; lacc has identical lane layout -> no shuffle
#pragma unroll
  for (int q = 0; q < 4; ++q) {
#pragma unroll
    for (int r = 0; r < 4; ++r) {
      float inv = 1.0f / lacc[q][r];
      int t = qt * 256 + wid * 64 + q * 16 + 4 * g + r;
      size_t base = ((size_t)(b * Ts + t)) * Cc + h * Dd;
#pragma unroll
      for (int dt = 0; dt < 4; ++dt)
        Yb[base + dt * 16 + l15] = f2bf(acc[q][dt][r] * inv);
    }
  }
}

// ------------------------------------------------------------------ launch
extern "C" void kernel_launch(void* const* d_in, const int* in_sizes, int n_in,
                              void* d_out, int out_size, void* d_ws, size_t ws_size,
                              hipStream_t stream) {
  const float* h    = (const float*)d_in[0];
  const float* mask = (const float*)d_in[1];
  const float* wa   = (const float*)d_in[2];   // [1024, 3072]
  const float* wp   = (const float*)d_in[3];   // [1024, 1024]
  float* out = (float*)d_out;

  char* ws = (char*)d_ws;
  ushort* hbf     = (ushort*)(ws);                    // 16 MiB (reused as Ybf)
  ushort* wattn_t = (ushort*)(ws + (16u << 20));      // 6 MiB
  ushort* wproj_t = (ushort*)(ws + (22u << 20));      // 2 MiB
  ushort* Qb      = (ushort*)(ws + (24u << 20));      // 16 MiB
  ushort* Kb      = (ushort*)(ws + (40u << 20));      // 16 MiB
  ushort* VTb     = (ushort*)(ws + (56u << 20));      // 16 MiB (end: 72 MiB)
  ushort* Ybf = hbf;

  cvt_kernel<<<2048, 256, 0, stream>>>(h, hbf, (Mm * Cc) / 4);
  transpose_cvt<<<dim3(3 * Cc / 32, Cc / 32), 256, 0, stream>>>(wa, wattn_t, Cc, 3 * Cc);
  transpose_cvt<<<dim3(Cc / 32, Cc / 32), 256, 0, stream>>>(wp, wproj_t, Cc, Cc);

  gemm_bt<1><<<dim3(3 * Cc / 128, Mm / 128), 256, 0, stream>>>(
      hbf, wattn_t, Mm, 3 * Cc, Cc, nullptr, Qb, Kb, VTb, mask);

  attn_kernel<<<dim3(Bb * Hh, Ts / 256), 256, 0, stream>>>(Qb, Kb, VTb, mask, Ybf);

  gemm_bt<0><<<dim3(Cc / 128, Mm / 128), 256, 0, stream>>>(
      Ybf, wproj_t, Mm, Cc, Cc, out, nullptr, nullptr, nullptr, nullptr);
}